// Round 8
// baseline (533.964 us; speedup 1.0000x reference)
//
#include <hip/hip_runtime.h>
#include <math.h>

#define D 128
#define GAT_ALPHA 0.2f
#define LN_EPS 1e-5f
#define BSHIFT 5
#define BKT 32       // nodes per bucket
#define CAPB 1280    // bucket capacity: mean 1024 + 8 sigma (binomial sd 32)
#define XPITCH 136   // LDS x-tile pitch in shorts (128 + 8 pad)

typedef __attribute__((ext_vector_type(8))) short short8;   // 8 bf16 (4 VGPRs)
typedef __attribute__((ext_vector_type(4))) float floatx4;  // MFMA C/D

__device__ __forceinline__ unsigned short f2bf(float f) {
    unsigned u = __float_as_uint(f);
    unsigned r = (u + 0x7fffu + ((u >> 16) & 1u)) >> 16;
    return (unsigned short)r;
}
__device__ __forceinline__ float bfl(unsigned u) { return __uint_as_float(u << 16); }
__device__ __forceinline__ float bfh(unsigned u) { return __uint_as_float(u & 0xffff0000u); }

// ---------------------------------------------------------------------------
// Kernel 1: MFMA GEMM (r3 gemm role, standalone for per-kernel counters).
// 128 rows per block, 8 waves; B-fragments built from W in LDS.
// ---------------------------------------------------------------------------
__global__ __launch_bounds__(512) void gemm_mfma(
        const float* __restrict__ x, const float* __restrict__ W,
        const float* __restrict__ b, const float* __restrict__ a,
        unsigned short* __restrict__ h16, float* __restrict__ s1,
        float* __restrict__ s2, int n)
{
    __shared__ unsigned short Bf[16384];        // 32 KB
    __shared__ unsigned short xs[128 * XPITCH]; // 34 KB
    const int tid = threadIdx.x;

    // build B fragments from W directly (W is L2-resident after first block)
    for (int idx = tid; idx < 2048; idx += 512) {
        int lane = idx & 63, ntkt = idx >> 6;
        int nt = ntkt >> 2, kt = ntkt & 3;
        int bl16 = lane & 15, bquad = lane >> 4;
        const float* wp = W + (size_t)(nt * 16 + bl16) * D + kt * 32 + bquad * 8;
        float4 w0 = *(const float4*)wp;
        float4 w1 = *(const float4*)(wp + 4);
        ushort4 o0, o1;
        o0.x = f2bf(w0.x); o0.y = f2bf(w0.y); o0.z = f2bf(w0.z); o0.w = f2bf(w0.w);
        o1.x = f2bf(w1.x); o1.y = f2bf(w1.y); o1.z = f2bf(w1.z); o1.w = f2bf(w1.w);
        *(ushort4*)&Bf[idx * 8]     = o0;
        *(ushort4*)&Bf[idx * 8 + 4] = o1;
    }

    const int lane = tid & 63, wave = tid >> 6;
    const int l16 = lane & 15, quad = lane >> 4;
    const int row0 = blockIdx.x * 128;

    // stage x tile: 128 rows x 32 float4, coalesced, convert to bf16
    for (int i = tid; i < 4096; i += 512) {
        int row = i >> 5, c4 = i & 31;
        float4 v = make_float4(0.f, 0.f, 0.f, 0.f);
        if (row0 + row < n) v = *(const float4*)(x + (size_t)(row0 + row) * D + c4 * 4);
        ushort4 o;
        o.x = f2bf(v.x); o.y = f2bf(v.y); o.z = f2bf(v.z); o.w = f2bf(v.w);
        *(ushort4*)&xs[row * XPITCH + c4 * 4] = o;
    }

    float bcol[8], a1c[8], a2c[8];
#pragma unroll
    for (int nt = 0; nt < 8; ++nt) {
        int c = nt * 16 + l16;
        bcol[nt] = b[c]; a1c[nt] = a[c]; a2c[nt] = a[D + c];
    }
    __syncthreads();

    floatx4 acc[8];
#pragma unroll
    for (int nt = 0; nt < 8; ++nt) acc[nt] = (floatx4){0.f, 0.f, 0.f, 0.f};

#pragma unroll
    for (int kt = 0; kt < 4; ++kt) {
        short8 af = *(const short8*)&xs[(wave * 16 + l16) * XPITCH + kt * 32 + quad * 8];
#pragma unroll
        for (int nt = 0; nt < 8; ++nt) {
            short8 bf = *(const short8*)&Bf[(size_t)((nt * 4 + kt) * 64 + lane) * 8];
            acc[nt] = __builtin_amdgcn_mfma_f32_16x16x32_bf16(af, bf, acc[nt], 0, 0, 0);
        }
    }

    // epilogue: bias + scores. C layout: col = nt*16+l16, row = quad*4+r.
    float hv[4][8];
#pragma unroll
    for (int r = 0; r < 4; ++r) {
        float p1 = 0.f, p2 = 0.f;
#pragma unroll
        for (int nt = 0; nt < 8; ++nt) {
            float v = acc[nt][r] + bcol[nt];
            hv[r][nt] = v;
            p1 = fmaf(v, a1c[nt], p1);
            p2 = fmaf(v, a2c[nt], p2);
        }
#pragma unroll
        for (int off = 8; off > 0; off >>= 1) {
            p1 += __shfl_xor(p1, off);
            p2 += __shfl_xor(p2, off);
        }
        int crow = row0 + wave * 16 + quad * 4 + r;
        if (crow < n && l16 == 0) { s1[crow] = p1; s2[crow] = p2; }
    }

    __syncthreads();  // xs reads done -> reuse as h tile
#pragma unroll
    for (int r = 0; r < 4; ++r)
#pragma unroll
        for (int nt = 0; nt < 8; ++nt)
            xs[(wave * 16 + quad * 4 + r) * XPITCH + nt * 16 + l16] = f2bf(hv[r][nt]);
    __syncthreads();

    // coalesced store: 128 rows x 16 uint4
    for (int i = tid; i < 2048; i += 512) {
        int row = i >> 4, c = i & 15;
        if (row0 + row < n)
            *(uint4*)(h16 + (size_t)(row0 + row) * D + c * 8) =
                *(const uint4*)&xs[row * XPITCH + c * 8];
    }
}

// ---------------------------------------------------------------------------
// Kernel 2: SINGLE-PASS partition scatter. One global atomicAdd per edge
// (3.2M atomics over 3125 counters, parallel across L2 channels); reads
// src/dst ONCE (was 3 passes + LDS histogram/barriers in the chunked form).
// ---------------------------------------------------------------------------
__global__ __launch_bounds__(256) void partition_scatter(
        const int* __restrict__ src, const int* __restrict__ dst,
        int* __restrict__ gcnt, int* __restrict__ pairs, int nE)
{
    int e = blockIdx.x * 256 + threadIdx.x;
    if (e >= nE) return;
    int s = src[e];
    int d = dst[e];
    int bb = s >> BSHIFT;
    int l = atomicAdd(&gcnt[bb], 1);
    if (l < CAPB) pairs[(size_t)bb * CAPB + l] = ((s & (BKT - 1)) << 24) | d;
}

// ---------------------------------------------------------------------------
// Kernel 3: FUSED per-bucket counting sort (in LDS) + aggregate + LN + ELU.
// EXACT round-3 configuration (measured 127-129 us, FETCH 349 MB, occ 56%).
// ---------------------------------------------------------------------------
__global__ __launch_bounds__(128, 6) void sort_aggregate(const int* __restrict__ pairs,
                                                         const int* __restrict__ gcnt,
                                                         const float* __restrict__ s1,
                                                         const float* __restrict__ s2,
                                                         const unsigned short* __restrict__ h16,
                                                         const float* __restrict__ ln_w,
                                                         const float* __restrict__ ln_b,
                                                         float* __restrict__ out, int n)
{
    __shared__ int2 csr2[CAPB];      // (dst, fp32 weight bits)  10 KB
    __shared__ int cnt[BKT], cnt2[BKT], excl[BKT + 1];
    __shared__ float sA[BKT];

    const int bkt = blockIdx.x, tid = threadIdx.x;
    const size_t base = (size_t)bkt * CAPB;
    int m = gcnt[bkt]; if (m > CAPB) m = CAPB;

    if (tid < BKT) {
        cnt[tid] = 0; cnt2[tid] = 0;
        int node = bkt * BKT + tid;
        sA[tid] = (node < n) ? s1[node] : 0.f;
    }
    __syncthreads();

    // phase 1: fine histogram (32 bins)
    for (int e = tid; e < m; e += 128)
        atomicAdd(&cnt[((unsigned)pairs[base + e]) >> 24], 1);
    __syncthreads();

    // phase 2: exclusive scan of 32 counters (lanes 0..31 of wave 0)
    if (tid < 32) {
        int v = cnt[tid], incl = v;
#pragma unroll
        for (int off = 1; off < 32; off <<= 1) {
            int t = __shfl_up(incl, off);
            if (tid >= off) incl += t;
        }
        excl[tid] = incl - v;
        if (tid == 31) excl[32] = incl;
    }
    __syncthreads();

    // phase 3: placement + edge-weight precompute (fp32)
    for (int e = tid; e < m; e += 128) {
        int w = pairs[base + e];
        int sl = ((unsigned)w) >> 24;
        int d = w & 0xFFFFFF;
        float z = sA[sl] + s2[d];
        float lz = z > 0.f ? z : GAT_ALPHA * z;
        float ee = __expf(-lz);
        int pos = excl[sl] + atomicAdd(&cnt2[sl], 1);
        csr2[pos] = make_int2(d, __float_as_int(ee));
    }
    __syncthreads();

    // phase 4: node-per-quarter aggregation. 8 quarters x 4 outer iters = 32 nodes.
    const int gq = tid >> 4;      // global quarter id 0..7
    const int l16 = tid & 15;

#pragma unroll 1
    for (int i = 0; i < BKT / 8; ++i) {
        int nl = i * 8 + gq;      // consecutive quarters -> consecutive nodes
        int node = bkt * BKT + nl;
        bool alive = node < n;
        int e0 = alive ? excl[nl] : 0;
        int e1 = alive ? excl[nl + 1] : 0;

        float acc[8];
#pragma unroll
        for (int j = 0; j < 8; ++j) acc[j] = 0.f;

        int e = e0;
        for (; e + 3 < e1; e += 4) {
            int2 pa = csr2[e];
            int2 pb = csr2[e + 1];
            int2 pc = csr2[e + 2];
            int2 pd = csr2[e + 3];
            uint4 ua = *(const uint4*)(h16 + (size_t)pa.x * D + l16 * 8);
            uint4 ub = *(const uint4*)(h16 + (size_t)pb.x * D + l16 * 8);
            uint4 uc = *(const uint4*)(h16 + (size_t)pc.x * D + l16 * 8);
            uint4 ud = *(const uint4*)(h16 + (size_t)pd.x * D + l16 * 8);
            float ea = __int_as_float(pa.y);
            float eb = __int_as_float(pb.y);
            float ec = __int_as_float(pc.y);
            float ed = __int_as_float(pd.y);
            acc[0] = fmaf(ea, bfl(ua.x), acc[0]);
            acc[1] = fmaf(ea, bfh(ua.x), acc[1]);
            acc[2] = fmaf(ea, bfl(ua.y), acc[2]);
            acc[3] = fmaf(ea, bfh(ua.y), acc[3]);
            acc[4] = fmaf(ea, bfl(ua.z), acc[4]);
            acc[5] = fmaf(ea, bfh(ua.z), acc[5]);
            acc[6] = fmaf(ea, bfl(ua.w), acc[6]);
            acc[7] = fmaf(ea, bfh(ua.w), acc[7]);
            acc[0] = fmaf(eb, bfl(ub.x), acc[0]);
            acc[1] = fmaf(eb, bfh(ub.x), acc[1]);
            acc[2] = fmaf(eb, bfl(ub.y), acc[2]);
            acc[3] = fmaf(eb, bfh(ub.y), acc[3]);
            acc[4] = fmaf(eb, bfl(ub.z), acc[4]);
            acc[5] = fmaf(eb, bfh(ub.z), acc[5]);
            acc[6] = fmaf(eb, bfl(ub.w), acc[6]);
            acc[7] = fmaf(eb, bfh(ub.w), acc[7]);
            acc[0] = fmaf(ec, bfl(uc.x), acc[0]);
            acc[1] = fmaf(ec, bfh(uc.x), acc[1]);
            acc[2] = fmaf(ec, bfl(uc.y), acc[2]);
            acc[3] = fmaf(ec, bfh(uc.y), acc[3]);
            acc[4] = fmaf(ec, bfl(uc.z), acc[4]);
            acc[5] = fmaf(ec, bfh(uc.z), acc[5]);
            acc[6] = fmaf(ec, bfl(uc.w), acc[6]);
            acc[7] = fmaf(ec, bfh(uc.w), acc[7]);
            acc[0] = fmaf(ed, bfl(ud.x), acc[0]);
            acc[1] = fmaf(ed, bfh(ud.x), acc[1]);
            acc[2] = fmaf(ed, bfl(ud.y), acc[2]);
            acc[3] = fmaf(ed, bfh(ud.y), acc[3]);
            acc[4] = fmaf(ed, bfl(ud.z), acc[4]);
            acc[5] = fmaf(ed, bfh(ud.z), acc[5]);
            acc[6] = fmaf(ed, bfl(ud.w), acc[6]);
            acc[7] = fmaf(ed, bfh(ud.w), acc[7]);
        }
        for (; e < e1; ++e) {
            int2 p = csr2[e];
            float ee = __int_as_float(p.y);
            uint4 u = *(const uint4*)(h16 + (size_t)p.x * D + l16 * 8);
            acc[0] = fmaf(ee, bfl(u.x), acc[0]);
            acc[1] = fmaf(ee, bfh(u.x), acc[1]);
            acc[2] = fmaf(ee, bfl(u.y), acc[2]);
            acc[3] = fmaf(ee, bfh(u.y), acc[3]);
            acc[4] = fmaf(ee, bfl(u.z), acc[4]);
            acc[5] = fmaf(ee, bfh(u.z), acc[5]);
            acc[6] = fmaf(ee, bfl(u.w), acc[6]);
            acc[7] = fmaf(ee, bfh(u.w), acc[7]);
        }

        // cross-feature reduction within the 16-lane quarter only
        float sum = 0.f, sq = 0.f;
#pragma unroll
        for (int j = 0; j < 8; ++j) { sum += acc[j]; sq += acc[j] * acc[j]; }
#pragma unroll
        for (int off = 8; off > 0; off >>= 1) {
            sum += __shfl_xor(sum, off);
            sq  += __shfl_xor(sq, off);
        }

        if (alive) {
            float mu   = sum * (1.0f / 128.0f);
            float var  = sq * (1.0f / 128.0f) - mu * mu;
            float rstd = rsqrtf(var + LN_EPS);

            float4 w0 = *(const float4*)(ln_w + l16 * 8);
            float4 w1 = *(const float4*)(ln_w + l16 * 8 + 4);
            float4 b0 = *(const float4*)(ln_b + l16 * 8);
            float4 b1 = *(const float4*)(ln_b + l16 * 8 + 4);
            float y[8];
            y[0] = (acc[0] - mu) * rstd * w0.x + b0.x;
            y[1] = (acc[1] - mu) * rstd * w0.y + b0.y;
            y[2] = (acc[2] - mu) * rstd * w0.z + b0.z;
            y[3] = (acc[3] - mu) * rstd * w0.w + b0.w;
            y[4] = (acc[4] - mu) * rstd * w1.x + b1.x;
            y[5] = (acc[5] - mu) * rstd * w1.y + b1.y;
            y[6] = (acc[6] - mu) * rstd * w1.z + b1.z;
            y[7] = (acc[7] - mu) * rstd * w1.w + b1.w;
#pragma unroll
            for (int j = 0; j < 8; ++j) y[j] = y[j] > 0.f ? y[j] : expm1f(y[j]);
            float* op = out + (size_t)node * D + l16 * 8;
            *(float4*)op       = make_float4(y[0], y[1], y[2], y[3]);
            *(float4*)(op + 4) = make_float4(y[4], y[5], y[6], y[7]);
        }
    }
}

// ---------------------------------------------------------------------------
extern "C" void kernel_launch(void* const* d_in, const int* in_sizes, int n_in,
                              void* d_out, int out_size, void* d_ws, size_t ws_size,
                              hipStream_t stream)
{
    const float* x    = (const float*)d_in[0];
    const float* W    = (const float*)d_in[1];
    const float* b    = (const float*)d_in[2];
    const float* a    = (const float*)d_in[3];
    const float* ln_w = (const float*)d_in[4];
    const float* ln_b = (const float*)d_in[5];
    const int*   edge = (const int*)d_in[6];

    const int n  = in_sizes[0] / D;   // 100000 nodes
    const int nE = in_sizes[6] / 2;   // 3.2M edges
    const int* src = edge;
    const int* dst = edge + nE;
    const int nb = (n + BKT - 1) >> BSHIFT;   // 3125 buckets of 32 nodes

    float* out = (float*)d_out;

    // workspace layout (all 16B-aligned)
    unsigned short* h16 = (unsigned short*)d_ws;            // n*D bf16  (25.6 MB)
    float* s1   = (float*)(h16 + (size_t)n * D);            // n
    float* s2   = s1 + n;                                   // n
    int* pairs  = (int*)(s2 + n);                           // nb*CAPB (16.0 MB)
    int* gcnt   = pairs + (size_t)nb * CAPB;                // nb

    hipMemsetAsync(gcnt, 0, (size_t)nb * sizeof(int), stream);

    gemm_mfma        <<<(n + 127) / 128, 256 * 2, 0, stream>>>(x, W, b, a, h16, s1, s2, n);
    partition_scatter<<<(nE + 255) / 256, 256, 0, stream>>>(src, dst, gcnt, pairs, nE);
    sort_aggregate   <<<nb, 128, 0, stream>>>(pairs, gcnt, s1, s2, h16, ln_w, ln_b, out, n);
}

// Round 9
// 306.253 us; speedup vs baseline: 1.7435x; 1.7435x over previous
//
#include <hip/hip_runtime.h>
#include <math.h>

#define D 128
#define GAT_ALPHA 0.2f
#define LN_EPS 1e-5f
#define BSHIFT 5
#define BKT 32       // nodes per bucket
#define NBMAX 3200   // max coarse buckets (n=100000 -> 3125)
#define CAPB 1280    // bucket capacity: mean 1024 + 8 sigma (binomial sd 32)
#define ECHUNK 8192  // smaller chunks -> 391 partition blocks (2x parallelism)
#define XPITCH 136   // LDS x-tile pitch in shorts (128 + 8 pad)

typedef __attribute__((ext_vector_type(8))) short short8;   // 8 bf16 (4 VGPRs)
typedef __attribute__((ext_vector_type(4))) float floatx4;  // MFMA C/D

__device__ __forceinline__ unsigned short f2bf(float f) {
    unsigned u = __float_as_uint(f);
    unsigned r = (u + 0x7fffu + ((u >> 16) & 1u)) >> 16;
    return (unsigned short)r;
}
__device__ __forceinline__ float bfl(unsigned u) { return __uint_as_float(u << 16); }
__device__ __forceinline__ float bfh(unsigned u) { return __uint_as_float(u & 0xffff0000u); }

// ---------------------------------------------------------------------------
// Kernel 1 (FAT): partition role (blocks < npart) runs CONCURRENTLY with
// gemm role (remaining blocks). r8 post-mortem: single-pass global-atomic
// partition = 276 us (1024-deep same-line atomic chains); the 2-level
// LDS reservation is load-bearing. This round's partition role is the lean
// form: ONE LDS array (cnt -> in-place cursor), 2 edge passes, 3 barriers.
// ---------------------------------------------------------------------------
union SmemU {
    struct { unsigned short Bf[16384]; unsigned short xs[128 * XPITCH]; } g;  // 66 KB
    struct { int cnt[NBMAX]; } p;                                             // 12.8 KB
};

__global__ __launch_bounds__(512) void gemm_partition(
        const float* __restrict__ x, const float* __restrict__ W,
        const float* __restrict__ b, const float* __restrict__ a,
        const int* __restrict__ src, const int* __restrict__ dst,
        int* __restrict__ gcnt, int* __restrict__ pairs,
        unsigned short* __restrict__ h16, float* __restrict__ s1,
        float* __restrict__ s2, int n, int nE, int nb, int npart)
{
    __shared__ SmemU sm;
    const int tid = threadIdx.x;

    if (blockIdx.x < npart) {
        // ---------------- partition role: bucket = src>>5 ----------------
        int* cnt = sm.p.cnt;
        for (int i = tid; i < nb; i += 512) cnt[i] = 0;
        __syncthreads();
        int e0 = blockIdx.x * ECHUNK;
        int e1 = e0 + ECHUNK; if (e1 > nE) e1 = nE;
        // pass 1: histogram
        for (int e = e0 + tid; e < e1; e += 512)
            atomicAdd(&cnt[src[e] >> BSHIFT], 1);
        __syncthreads();
        // reserve: cnt[i] becomes the block's global cursor base, in place
        for (int i = tid; i < nb; i += 512) {
            int c = cnt[i];
            cnt[i] = c ? atomicAdd(&gcnt[i], c) : 0;
        }
        __syncthreads();
        // pass 2: placement via LDS cursor
        for (int e = e0 + tid; e < e1; e += 512) {
            int s = src[e];
            int bb = s >> BSHIFT;
            int l = atomicAdd(&cnt[bb], 1);
            if (l < CAPB) pairs[(size_t)bb * CAPB + l] = ((s & (BKT - 1)) << 24) | dst[e];
        }
        return;
    }

    // ---------------- gemm role: 128 rows per block, 8 waves ----------------
    unsigned short* Bf = sm.g.Bf;
    unsigned short* xs = sm.g.xs;

    // build B fragments from W directly (W is L2-resident after first block)
    for (int idx = tid; idx < 2048; idx += 512) {
        int lane = idx & 63, ntkt = idx >> 6;
        int nt = ntkt >> 2, kt = ntkt & 3;
        int bl16 = lane & 15, bquad = lane >> 4;
        const float* wp = W + (size_t)(nt * 16 + bl16) * D + kt * 32 + bquad * 8;
        float4 w0 = *(const float4*)wp;
        float4 w1 = *(const float4*)(wp + 4);
        ushort4 o0, o1;
        o0.x = f2bf(w0.x); o0.y = f2bf(w0.y); o0.z = f2bf(w0.z); o0.w = f2bf(w0.w);
        o1.x = f2bf(w1.x); o1.y = f2bf(w1.y); o1.z = f2bf(w1.z); o1.w = f2bf(w1.w);
        *(ushort4*)&Bf[idx * 8]     = o0;
        *(ushort4*)&Bf[idx * 8 + 4] = o1;
    }

    const int lane = tid & 63, wave = tid >> 6;
    const int l16 = lane & 15, quad = lane >> 4;
    const int row0 = (blockIdx.x - npart) * 128;

    // stage x tile: 128 rows x 32 float4, coalesced, convert to bf16
    for (int i = tid; i < 4096; i += 512) {
        int row = i >> 5, c4 = i & 31;
        float4 v = make_float4(0.f, 0.f, 0.f, 0.f);
        if (row0 + row < n) v = *(const float4*)(x + (size_t)(row0 + row) * D + c4 * 4);
        ushort4 o;
        o.x = f2bf(v.x); o.y = f2bf(v.y); o.z = f2bf(v.z); o.w = f2bf(v.w);
        *(ushort4*)&xs[row * XPITCH + c4 * 4] = o;
    }

    float bcol[8], a1c[8], a2c[8];
#pragma unroll
    for (int nt = 0; nt < 8; ++nt) {
        int c = nt * 16 + l16;
        bcol[nt] = b[c]; a1c[nt] = a[c]; a2c[nt] = a[D + c];
    }
    __syncthreads();

    floatx4 acc[8];
#pragma unroll
    for (int nt = 0; nt < 8; ++nt) acc[nt] = (floatx4){0.f, 0.f, 0.f, 0.f};

#pragma unroll
    for (int kt = 0; kt < 4; ++kt) {
        short8 af = *(const short8*)&xs[(wave * 16 + l16) * XPITCH + kt * 32 + quad * 8];
#pragma unroll
        for (int nt = 0; nt < 8; ++nt) {
            short8 bf = *(const short8*)&Bf[(size_t)((nt * 4 + kt) * 64 + lane) * 8];
            acc[nt] = __builtin_amdgcn_mfma_f32_16x16x32_bf16(af, bf, acc[nt], 0, 0, 0);
        }
    }

    // epilogue: bias + scores. C layout: col = nt*16+l16, row = quad*4+r.
    float hv[4][8];
#pragma unroll
    for (int r = 0; r < 4; ++r) {
        float p1 = 0.f, p2 = 0.f;
#pragma unroll
        for (int nt = 0; nt < 8; ++nt) {
            float v = acc[nt][r] + bcol[nt];
            hv[r][nt] = v;
            p1 = fmaf(v, a1c[nt], p1);
            p2 = fmaf(v, a2c[nt], p2);
        }
#pragma unroll
        for (int off = 8; off > 0; off >>= 1) {
            p1 += __shfl_xor(p1, off);
            p2 += __shfl_xor(p2, off);
        }
        int crow = row0 + wave * 16 + quad * 4 + r;
        if (crow < n && l16 == 0) { s1[crow] = p1; s2[crow] = p2; }
    }

    __syncthreads();  // xs reads done -> reuse as h tile
#pragma unroll
    for (int r = 0; r < 4; ++r)
#pragma unroll
        for (int nt = 0; nt < 8; ++nt)
            xs[(wave * 16 + quad * 4 + r) * XPITCH + nt * 16 + l16] = f2bf(hv[r][nt]);
    __syncthreads();

    // coalesced store: 128 rows x 16 uint4
    for (int i = tid; i < 2048; i += 512) {
        int row = i >> 4, c = i & 15;
        if (row0 + row < n)
            *(uint4*)(h16 + (size_t)(row0 + row) * D + c * 8) =
                *(const uint4*)&xs[row * XPITCH + c * 8];
    }
}

// ---------------------------------------------------------------------------
// Kernel 2: FUSED per-bucket counting sort (in LDS) + aggregate + LN + ELU.
// EXACT round-3 configuration (measured 127-129 us, FETCH 349 MB, occ 56%).
// ---------------------------------------------------------------------------
__global__ __launch_bounds__(128, 6) void sort_aggregate(const int* __restrict__ pairs,
                                                         const int* __restrict__ gcnt,
                                                         const float* __restrict__ s1,
                                                         const float* __restrict__ s2,
                                                         const unsigned short* __restrict__ h16,
                                                         const float* __restrict__ ln_w,
                                                         const float* __restrict__ ln_b,
                                                         float* __restrict__ out, int n)
{
    __shared__ int2 csr2[CAPB];      // (dst, fp32 weight bits)  10 KB
    __shared__ int cnt[BKT], cnt2[BKT], excl[BKT + 1];
    __shared__ float sA[BKT];

    const int bkt = blockIdx.x, tid = threadIdx.x;
    const size_t base = (size_t)bkt * CAPB;
    int m = gcnt[bkt]; if (m > CAPB) m = CAPB;

    if (tid < BKT) {
        cnt[tid] = 0; cnt2[tid] = 0;
        int node = bkt * BKT + tid;
        sA[tid] = (node < n) ? s1[node] : 0.f;
    }
    __syncthreads();

    // phase 1: fine histogram (32 bins)
    for (int e = tid; e < m; e += 128)
        atomicAdd(&cnt[((unsigned)pairs[base + e]) >> 24], 1);
    __syncthreads();

    // phase 2: exclusive scan of 32 counters (lanes 0..31 of wave 0)
    if (tid < 32) {
        int v = cnt[tid], incl = v;
#pragma unroll
        for (int off = 1; off < 32; off <<= 1) {
            int t = __shfl_up(incl, off);
            if (tid >= off) incl += t;
        }
        excl[tid] = incl - v;
        if (tid == 31) excl[32] = incl;
    }
    __syncthreads();

    // phase 3: placement + edge-weight precompute (fp32)
    for (int e = tid; e < m; e += 128) {
        int w = pairs[base + e];
        int sl = ((unsigned)w) >> 24;
        int d = w & 0xFFFFFF;
        float z = sA[sl] + s2[d];
        float lz = z > 0.f ? z : GAT_ALPHA * z;
        float ee = __expf(-lz);
        int pos = excl[sl] + atomicAdd(&cnt2[sl], 1);
        csr2[pos] = make_int2(d, __float_as_int(ee));
    }
    __syncthreads();

    // phase 4: node-per-quarter aggregation. 8 quarters x 4 outer iters = 32 nodes.
    const int gq = tid >> 4;      // global quarter id 0..7
    const int l16 = tid & 15;

#pragma unroll 1
    for (int i = 0; i < BKT / 8; ++i) {
        int nl = i * 8 + gq;      // consecutive quarters -> consecutive nodes
        int node = bkt * BKT + nl;
        bool alive = node < n;
        int e0 = alive ? excl[nl] : 0;
        int e1 = alive ? excl[nl + 1] : 0;

        float acc[8];
#pragma unroll
        for (int j = 0; j < 8; ++j) acc[j] = 0.f;

        int e = e0;
        for (; e + 3 < e1; e += 4) {
            int2 pa = csr2[e];
            int2 pb = csr2[e + 1];
            int2 pc = csr2[e + 2];
            int2 pd = csr2[e + 3];
            uint4 ua = *(const uint4*)(h16 + (size_t)pa.x * D + l16 * 8);
            uint4 ub = *(const uint4*)(h16 + (size_t)pb.x * D + l16 * 8);
            uint4 uc = *(const uint4*)(h16 + (size_t)pc.x * D + l16 * 8);
            uint4 ud = *(const uint4*)(h16 + (size_t)pd.x * D + l16 * 8);
            float ea = __int_as_float(pa.y);
            float eb = __int_as_float(pb.y);
            float ec = __int_as_float(pc.y);
            float ed = __int_as_float(pd.y);
            acc[0] = fmaf(ea, bfl(ua.x), acc[0]);
            acc[1] = fmaf(ea, bfh(ua.x), acc[1]);
            acc[2] = fmaf(ea, bfl(ua.y), acc[2]);
            acc[3] = fmaf(ea, bfh(ua.y), acc[3]);
            acc[4] = fmaf(ea, bfl(ua.z), acc[4]);
            acc[5] = fmaf(ea, bfh(ua.z), acc[5]);
            acc[6] = fmaf(ea, bfl(ua.w), acc[6]);
            acc[7] = fmaf(ea, bfh(ua.w), acc[7]);
            acc[0] = fmaf(eb, bfl(ub.x), acc[0]);
            acc[1] = fmaf(eb, bfh(ub.x), acc[1]);
            acc[2] = fmaf(eb, bfl(ub.y), acc[2]);
            acc[3] = fmaf(eb, bfh(ub.y), acc[3]);
            acc[4] = fmaf(eb, bfl(ub.z), acc[4]);
            acc[5] = fmaf(eb, bfh(ub.z), acc[5]);
            acc[6] = fmaf(eb, bfl(ub.w), acc[6]);
            acc[7] = fmaf(eb, bfh(ub.w), acc[7]);
            acc[0] = fmaf(ec, bfl(uc.x), acc[0]);
            acc[1] = fmaf(ec, bfh(uc.x), acc[1]);
            acc[2] = fmaf(ec, bfl(uc.y), acc[2]);
            acc[3] = fmaf(ec, bfh(uc.y), acc[3]);
            acc[4] = fmaf(ec, bfl(uc.z), acc[4]);
            acc[5] = fmaf(ec, bfh(uc.z), acc[5]);
            acc[6] = fmaf(ec, bfl(uc.w), acc[6]);
            acc[7] = fmaf(ec, bfh(uc.w), acc[7]);
            acc[0] = fmaf(ed, bfl(ud.x), acc[0]);
            acc[1] = fmaf(ed, bfh(ud.x), acc[1]);
            acc[2] = fmaf(ed, bfl(ud.y), acc[2]);
            acc[3] = fmaf(ed, bfh(ud.y), acc[3]);
            acc[4] = fmaf(ed, bfl(ud.z), acc[4]);
            acc[5] = fmaf(ed, bfh(ud.z), acc[5]);
            acc[6] = fmaf(ed, bfl(ud.w), acc[6]);
            acc[7] = fmaf(ed, bfh(ud.w), acc[7]);
        }
        for (; e < e1; ++e) {
            int2 p = csr2[e];
            float ee = __int_as_float(p.y);
            uint4 u = *(const uint4*)(h16 + (size_t)p.x * D + l16 * 8);
            acc[0] = fmaf(ee, bfl(u.x), acc[0]);
            acc[1] = fmaf(ee, bfh(u.x), acc[1]);
            acc[2] = fmaf(ee, bfl(u.y), acc[2]);
            acc[3] = fmaf(ee, bfh(u.y), acc[3]);
            acc[4] = fmaf(ee, bfl(u.z), acc[4]);
            acc[5] = fmaf(ee, bfh(u.z), acc[5]);
            acc[6] = fmaf(ee, bfl(u.w), acc[6]);
            acc[7] = fmaf(ee, bfh(u.w), acc[7]);
        }

        // cross-feature reduction within the 16-lane quarter only
        float sum = 0.f, sq = 0.f;
#pragma unroll
        for (int j = 0; j < 8; ++j) { sum += acc[j]; sq += acc[j] * acc[j]; }
#pragma unroll
        for (int off = 8; off > 0; off >>= 1) {
            sum += __shfl_xor(sum, off);
            sq  += __shfl_xor(sq, off);
        }

        if (alive) {
            float mu   = sum * (1.0f / 128.0f);
            float var  = sq * (1.0f / 128.0f) - mu * mu;
            float rstd = rsqrtf(var + LN_EPS);

            float4 w0 = *(const float4*)(ln_w + l16 * 8);
            float4 w1 = *(const float4*)(ln_w + l16 * 8 + 4);
            float4 b0 = *(const float4*)(ln_b + l16 * 8);
            float4 b1 = *(const float4*)(ln_b + l16 * 8 + 4);
            float y[8];
            y[0] = (acc[0] - mu) * rstd * w0.x + b0.x;
            y[1] = (acc[1] - mu) * rstd * w0.y + b0.y;
            y[2] = (acc[2] - mu) * rstd * w0.z + b0.z;
            y[3] = (acc[3] - mu) * rstd * w0.w + b0.w;
            y[4] = (acc[4] - mu) * rstd * w1.x + b1.x;
            y[5] = (acc[5] - mu) * rstd * w1.y + b1.y;
            y[6] = (acc[6] - mu) * rstd * w1.z + b1.z;
            y[7] = (acc[7] - mu) * rstd * w1.w + b1.w;
#pragma unroll
            for (int j = 0; j < 8; ++j) y[j] = y[j] > 0.f ? y[j] : expm1f(y[j]);
            float* op = out + (size_t)node * D + l16 * 8;
            *(float4*)op       = make_float4(y[0], y[1], y[2], y[3]);
            *(float4*)(op + 4) = make_float4(y[4], y[5], y[6], y[7]);
        }
    }
}

// ---------------------------------------------------------------------------
extern "C" void kernel_launch(void* const* d_in, const int* in_sizes, int n_in,
                              void* d_out, int out_size, void* d_ws, size_t ws_size,
                              hipStream_t stream)
{
    const float* x    = (const float*)d_in[0];
    const float* W    = (const float*)d_in[1];
    const float* b    = (const float*)d_in[2];
    const float* a    = (const float*)d_in[3];
    const float* ln_w = (const float*)d_in[4];
    const float* ln_b = (const float*)d_in[5];
    const int*   edge = (const int*)d_in[6];

    const int n  = in_sizes[0] / D;   // 100000 nodes
    const int nE = in_sizes[6] / 2;   // 3.2M edges
    const int* src = edge;
    const int* dst = edge + nE;
    const int nb = (n + BKT - 1) >> BSHIFT;       // 3125 buckets of 32 nodes
    const int npart = (nE + ECHUNK - 1) / ECHUNK; // 391 partition blocks
    const int ngemm = (n + 127) / 128;            // 782 gemm blocks

    float* out = (float*)d_out;

    // workspace layout (all 16B-aligned)
    unsigned short* h16 = (unsigned short*)d_ws;            // n*D bf16  (25.6 MB)
    float* s1   = (float*)(h16 + (size_t)n * D);            // n
    float* s2   = s1 + n;                                   // n
    int* pairs  = (int*)(s2 + n);                           // nb*CAPB (16.0 MB)
    int* gcnt   = pairs + (size_t)nb * CAPB;                // nb

    hipMemsetAsync(gcnt, 0, (size_t)nb * sizeof(int), stream);

    gemm_partition<<<npart + ngemm, 512, 0, stream>>>(x, W, b, a, src, dst,
                                                      gcnt, pairs, h16, s1, s2,
                                                      n, nE, nb, npart);
    sort_aggregate<<<nb, 128, 0, stream>>>(pairs, gcnt, s1, s2, h16, ln_w, ln_b, out, n);
}